// Round 1
// baseline (410.943 us; speedup 1.0000x reference)
//
#include <hip/hip_runtime.h>
#include <math.h>

// ---------------------------------------------------------------------------
// QINRLayer: Linear+BN -> 10-qubit QNN (statevector sim) -> classical branch
// Design: one wave (64 lanes) per sample; 1024 complex amps in registers
// (16 complex / lane).  k = lane*16 + j ; wire w (0 = MSB) <-> bit (9-w) of k.
// wires 0..5 -> lane bits 5..0 (cross-lane via shfl_xor)
// wires 6..9 -> local bits 3..0 (in-register)
// ---------------------------------------------------------------------------

#define R0 0.70710678118654752f

// ws layout (floats)
#define WS_XQ    0         // 8192*40
#define WS_X1    327680    // 8192*40
#define WS_BNA   655360    // 40
#define WS_BNC   655400    // 40
#define WS_GATES 655440    // 40 gates * 8 floats (fused rz2*ry1*rz1 per block,wire)
#define WS_RZ3   655760    // 10 * {cos,sin}

// ---------------- gate primitives (state in registers) ---------------------

template<int M>
__device__ __forceinline__ void gen_local(float (&sr)[16], float (&si)[16],
    float g00r,float g00i,float g01r,float g01i,
    float g10r,float g10i,float g11r,float g11i)
{
#pragma unroll
  for (int j=0;j<16;++j) if (!(j&M)) {
    const int j1=j|M;
    float ar=sr[j],ai=si[j],br=sr[j1],bi=si[j1];
    sr[j]  = g00r*ar - g00i*ai + g01r*br - g01i*bi;
    si[j]  = g00r*ai + g00i*ar + g01r*bi + g01i*br;
    sr[j1] = g10r*ar - g10i*ai + g11r*br - g11i*bi;
    si[j1] = g10r*ai + g10i*ar + g11r*bi + g11i*br;
  }
}

template<int LM>
__device__ __forceinline__ void gen_cross(float (&sr)[16], float (&si)[16], int lane,
    float g00r,float g00i,float g01r,float g01i,
    float g10r,float g10i,float g11r,float g11i)
{
  const bool hi = (lane & LM) != 0;
  const float gar = hi ? g11r : g00r;
  const float gai = hi ? g11i : g00i;
  const float gbr = hi ? g10r : g01r;
  const float gbi = hi ? g10i : g01i;
#pragma unroll
  for (int j=0;j<16;++j) {
    float pr = __shfl_xor(sr[j], LM, 64);
    float pi = __shfl_xor(si[j], LM, 64);
    float mr = sr[j], mi = si[j];
    sr[j] = gar*mr - gai*mi + gbr*pr - gbi*pi;
    si[j] = gar*mi + gai*mr + gbr*pi + gbi*pr;
  }
}

template<int W>
__device__ __forceinline__ void gen_wire(float (&sr)[16], float (&si)[16], int lane,
                                         const float* g)
{
  float g00r=g[0],g00i=g[1],g01r=g[2],g01i=g[3],g10r=g[4],g10i=g[5],g11r=g[6],g11i=g[7];
  if constexpr (W < 6) gen_cross<(1<<(5-W))>(sr,si,lane,g00r,g00i,g01r,g01i,g10r,g10i,g11r,g11i);
  else                 gen_local<(1<<(9-W))>(sr,si,g00r,g00i,g01r,g01i,g10r,g10i,g11r,g11i);
}

// Hadamard (real): v0' = r(v0+v1), v1' = r(v0-v1)
template<int M>
__device__ __forceinline__ void h_local(float (&sr)[16], float (&si)[16])
{
#pragma unroll
  for (int j=0;j<16;++j) if (!(j&M)) {
    const int j1=j|M;
    float ar=sr[j],ai=si[j],br=sr[j1],bi=si[j1];
    sr[j]=R0*(ar+br);  si[j]=R0*(ai+bi);
    sr[j1]=R0*(ar-br); si[j1]=R0*(ai-bi);
  }
}
template<int LM>
__device__ __forceinline__ void h_cross(float (&sr)[16], float (&si)[16], int lane)
{
  const float sg = (lane & LM) ? -1.f : 1.f;
#pragma unroll
  for (int j=0;j<16;++j) {
    float pr=__shfl_xor(sr[j],LM,64), pi=__shfl_xor(si[j],LM,64);
    sr[j] = R0*fmaf(sg, sr[j], pr);
    si[j] = R0*fmaf(sg, si[j], pi);
  }
}
template<int W>
__device__ __forceinline__ void h_wire(float (&sr)[16], float (&si)[16], int lane)
{
  if constexpr (W < 6) h_cross<(1<<(5-W))>(sr,si,lane);
  else                 h_local<(1<<(9-W))>(sr,si);
}

// SX*H = r * [[1, i],[1, -i]]
template<int W>
__device__ __forceinline__ void sxh_wire(float (&sr)[16], float (&si)[16], int lane)
{
  if constexpr (W < 6) gen_cross<(1<<(5-W))>(sr,si,lane, R0,0.f, 0.f,R0, R0,0.f, 0.f,-R0);
  else                 gen_local<(1<<(9-W))>(sr,si,      R0,0.f, 0.f,R0, R0,0.f, 0.f,-R0);
}

// rz: diag(e^{-i t/2}, e^{i t/2}); amplitude *= (c, sh) where sh = bit? s : -s
template<int M>
__device__ __forceinline__ void rz_local(float (&sr)[16], float (&si)[16], float c, float s)
{
#pragma unroll
  for (int j=0;j<16;++j) {
    const float sh = (j&M) ? s : -s;
    float re=sr[j], im=si[j];
    sr[j] = c*re - sh*im;
    si[j] = c*im + sh*re;
  }
}
template<int LM>
__device__ __forceinline__ void rz_cross(float (&sr)[16], float (&si)[16], int lane, float c, float s)
{
  const float sh = (lane&LM) ? s : -s;
#pragma unroll
  for (int j=0;j<16;++j) {
    float re=sr[j], im=si[j];
    sr[j] = c*re - sh*im;
    si[j] = c*im + sh*re;
  }
}
template<int W>
__device__ __forceinline__ void rz_wire(float (&sr)[16], float (&si)[16], int lane, float c, float s)
{
  if constexpr (W < 6) rz_cross<(1<<(5-W))>(sr,si,lane,c,s);
  else                 rz_local<(1<<(9-W))>(sr,si,c,s);
}

// ---------------- CNOTs ----------------------------------------------------

// control lane bit CM, target lane bit TM
__device__ __forceinline__ void cnot_ll(float (&sr)[16], float (&si)[16], int lane, int CM, int TM)
{
  const bool c = (lane & CM) != 0;
#pragma unroll
  for (int j=0;j<16;++j) {
    float pr=__shfl_xor(sr[j],TM,64), pi=__shfl_xor(si[j],TM,64);
    sr[j] = c ? pr : sr[j];
    si[j] = c ? pi : si[j];
  }
}
// control lane bit0 (wire5), target local bit3 (wire6)
__device__ __forceinline__ void cnot_lane_local8(float (&sr)[16], float (&si)[16], int lane)
{
  const bool c = (lane & 1) != 0;
#pragma unroll
  for (int j=0;j<8;++j) {
    const int j1=j|8;
    float ar=sr[j], br=sr[j1];
    sr[j]=c?br:ar; sr[j1]=c?ar:br;
    float ai=si[j], bi=si[j1];
    si[j]=c?bi:ai; si[j1]=c?ai:bi;
  }
}
// both local: compile-time register swap
template<int CM,int TM>
__device__ __forceinline__ void cnot_local(float (&sr)[16], float (&si)[16])
{
#pragma unroll
  for (int j=0;j<16;++j) if ((j&CM) && !(j&TM)) {
    const int j1=j|TM;
    float t=sr[j]; sr[j]=sr[j1]; sr[j1]=t;
    t=si[j]; si[j]=si[j1]; si[j1]=t;
  }
}
// control local bit0 (wire9), target lane bit5 (wire0): odd j swap across lane^32
__device__ __forceinline__ void cnot_local_lane(float (&sr)[16], float (&si)[16])
{
#pragma unroll
  for (int j=1;j<16;j+=2) {
    sr[j]=__shfl_xor(sr[j],32,64);
    si[j]=__shfl_xor(si[j],32,64);
  }
}
__device__ __forceinline__ void cnot_ring(float (&sr)[16], float (&si)[16], int lane)
{
  cnot_ll(sr,si,lane,32,16);   // (0,1)
  cnot_ll(sr,si,lane,16,8);    // (1,2)
  cnot_ll(sr,si,lane,8,4);     // (2,3)
  cnot_ll(sr,si,lane,4,2);     // (3,4)
  cnot_ll(sr,si,lane,2,1);     // (4,5)
  cnot_lane_local8(sr,si,lane);// (5,6)
  cnot_local<8,4>(sr,si);      // (6,7)
  cnot_local<4,2>(sr,si);      // (7,8)
  cnot_local<2,1>(sr,si);      // (8,9)
  cnot_local_lane(sr,si);      // (9,0)
}

// ---------------- measurement ----------------------------------------------
__device__ __forceinline__ void measure_store(const float (&sr)[16], const float (&si)[16],
                                              int lane, float* dst)
{
  float p[16];
#pragma unroll
  for (int j=0;j<16;++j) p[j] = fmaf(sr[j],sr[j], si[j]*si[j]);
  float P = 0.f;
#pragma unroll
  for (int j=0;j<16;++j) P += p[j];
  float q[10];
#pragma unroll
  for (int w=0; w<6; ++w) q[w] = (lane & (1<<(5-w))) ? -P : P;
#pragma unroll
  for (int w=6; w<10; ++w) {
    const int M = 1<<(9-w);
    float t=0.f;
#pragma unroll
    for (int j=0;j<16;++j) t += (j&M)? -p[j] : p[j];
    q[w]=t;
  }
#pragma unroll
  for (int w=0; w<10; ++w) {
#pragma unroll
    for (int m=1; m<64; m<<=1) q[w] += __shfl_xor(q[w], m, 64);
  }
  if (lane==0) {
#pragma unroll
    for (int w=0; w<10; ++w) dst[w]=q[w];
  }
}

// ---------------- kernels --------------------------------------------------

// xq = x @ qlin_w.T + qlin_b ; one thread per (sample, feature)
__global__ void k_xq(const float* __restrict__ x, const float* __restrict__ w,
                     const float* __restrict__ b, float* __restrict__ xq)
{
  int idx = blockIdx.x*256 + threadIdx.x;       // 327680 total
  int s = idx/40, f = idx - s*40;
  float acc = b[f];
#pragma unroll
  for (int k=0;k<40;++k) acc = fmaf(x[s*40+k], w[f*40+k], acc);
  xq[idx] = acc;
}

// per-feature BN scale/shift: a = gamma*rsqrt(var+eps), c = beta - mu*a
__global__ void k_stats(const float* __restrict__ xq, const float* __restrict__ gamma,
                        const float* __restrict__ beta, float* __restrict__ bn_a,
                        float* __restrict__ bn_c)
{
  int f = blockIdx.x, t = threadIdx.x;
  float s1=0.f, s2=0.f;
  for (int i=t;i<8192;i+=256) {
    float v = xq[i*40+f];
    s1 += v; s2 = fmaf(v,v,s2);
  }
  __shared__ float a1[256], a2[256];
  a1[t]=s1; a2[t]=s2; __syncthreads();
  for (int off=128; off; off>>=1) {
    if (t<off){ a1[t]+=a1[t+off]; a2[t]+=a2[t+off]; }
    __syncthreads();
  }
  if (t==0) {
    float mu = a1[0]*(1.f/8192.f);
    float var = a2[0]*(1.f/8192.f) - mu*mu;
    float a = gamma[f]*rsqrtf(var + 1e-5f);
    bn_a[f]=a; bn_c[f]=beta[f]-mu*a;
  }
}

// fused param gates U = Rz(rz2)*Ry(ry1)*Rz(rz1) per (block,wire); rz3 sincos
__global__ void k_consts(const float* __restrict__ rz1, const float* __restrict__ ry1,
                         const float* __restrict__ rz2, const float* __restrict__ rz3,
                         float* __restrict__ gates, float* __restrict__ rz3cs)
{
  int t = threadIdx.x;
  if (t < 40) {
    float g = rz1[t], a = ry1[t], b = rz2[t];
    float ca, sa, cp, sp, cm, sm;
    sincosf(0.5f*a, &sa, &ca);
    sincosf(0.5f*(b+g), &sp, &cp);
    sincosf(0.5f*(b-g), &sm, &cm);
    float* G = gates + t*8;
    G[0]= ca*cp; G[1]=-ca*sp;   // U00 = ca e^{-i(b+g)/2}
    G[2]=-sa*cm; G[3]= sa*sm;   // U01 = -sa e^{-i(b-g)/2}
    G[4]= sa*cm; G[5]= sa*sm;   // U10 =  sa e^{ i(b-g)/2}
    G[6]= ca*cp; G[7]= ca*sp;   // U11 = ca e^{ i(b+g)/2}
  }
  if (t < 10) {
    float th = rz3[30+t];       // rz3[-1] layer only
    float c,s; sincosf(0.5f*th, &s, &c);
    rz3cs[2*t]=c; rz3cs[2*t+1]=s;
  }
}

#define GEN10(PTR) \
  gen_wire<0>(sr,si,lane,(PTR)+0);  gen_wire<1>(sr,si,lane,(PTR)+8);  \
  gen_wire<2>(sr,si,lane,(PTR)+16); gen_wire<3>(sr,si,lane,(PTR)+24); \
  gen_wire<4>(sr,si,lane,(PTR)+32); gen_wire<5>(sr,si,lane,(PTR)+40); \
  gen_wire<6>(sr,si,lane,(PTR)+48); gen_wire<7>(sr,si,lane,(PTR)+56); \
  gen_wire<8>(sr,si,lane,(PTR)+64); gen_wire<9>(sr,si,lane,(PTR)+72);

__global__ __launch_bounds__(256) void k_qnn(const float* __restrict__ xq,
    const float* __restrict__ bn_a, const float* __restrict__ bn_c,
    const float* __restrict__ gates, const float* __restrict__ rz3cs,
    float* __restrict__ x1)
{
  const int lane = threadIdx.x & 63;
  const int wv   = threadIdx.x >> 6;
  const int s    = blockIdx.x*4 + wv;

  __shared__ float encU[4][10][8];

  // ---- per-sample fused encoder matrix per wire: Rx(f3) Rz(f2) Ry(f1) Rx(f0)
  if (lane < 10) {
    const int i = lane;
    float h0,h1,h2,h3;
    {
      const int f = 4*i;
      h0 = 0.5f * fmaf(xq[s*40+f+0], bn_a[f+0], bn_c[f+0]);
      h1 = 0.5f * fmaf(xq[s*40+f+1], bn_a[f+1], bn_c[f+1]);
      h2 = 0.5f * fmaf(xq[s*40+f+2], bn_a[f+2], bn_c[f+2]);
      h3 = 0.5f * fmaf(xq[s*40+f+3], bn_a[f+3], bn_c[f+3]);
    }
    float c0,s0,c1,s1,c2,s2,c3,s3;
    sincosf(h0,&s0,&c0); sincosf(h1,&s1,&c1);
    sincosf(h2,&s2,&c2); sincosf(h3,&s3,&c3);
    // A = Ry(f1) * Rx(f0)
    float A00r=c1*c0, A00i= s1*s0;
    float A01r=-s1*c0, A01i=-c1*s0;
    float A10r= s1*c0, A10i=-c1*s0;
    float A11r= c1*c0, A11i=-s1*s0;
    // B = Rz(f2)*A: row0 *(c2,-s2), row1 *(c2,s2)
    float B00r = A00r*c2 + A00i*s2, B00i = A00i*c2 - A00r*s2;
    float B01r = A01r*c2 + A01i*s2, B01i = A01i*c2 - A01r*s2;
    float B10r = A10r*c2 - A10i*s2, B10i = A10i*c2 + A10r*s2;
    float B11r = A11r*c2 - A11i*s2, B11i = A11i*c2 + A11r*s2;
    // C = Rx(f3)*B: (-i s3)(x+iy) = (s3 y, -s3 x)
    float* e = &encU[wv][i][0];
    e[0] = c3*B00r + s3*B10i;  e[1] = c3*B00i - s3*B10r;
    e[2] = c3*B01r + s3*B11i;  e[3] = c3*B01i - s3*B11r;
    e[4] = c3*B10r + s3*B00i;  e[5] = c3*B10i - s3*B00r;
    e[6] = c3*B11r + s3*B01i;  e[7] = c3*B11i - s3*B01r;
  }
  __syncthreads();

  // ---- state |0...0>
  float sr[16], si[16];
#pragma unroll
  for (int j=0;j<16;++j){ sr[j]=0.f; si[j]=0.f; }
  if (lane==0) sr[0]=1.f;

  // ---- 4 blocks
#pragma unroll 1
  for (int k=0;k<4;++k) {
    const float* G = gates + k*80;
    GEN10(G)
    cnot_ring(sr,si,lane);
    if (k<3) {
      const float* E = &encU[wv][0][0];
      GEN10(E)
    }
  }

  float* dst = x1 + s*40;
  measure_store(sr,si,lane,dst);

  // H on all wires
  h_wire<0>(sr,si,lane); h_wire<1>(sr,si,lane); h_wire<2>(sr,si,lane);
  h_wire<3>(sr,si,lane); h_wire<4>(sr,si,lane); h_wire<5>(sr,si,lane);
  h_wire<6>(sr,si,lane); h_wire<7>(sr,si,lane); h_wire<8>(sr,si,lane);
  h_wire<9>(sr,si,lane);
  measure_store(sr,si,lane,dst+10);

  // SX*H on all wires
  sxh_wire<0>(sr,si,lane); sxh_wire<1>(sr,si,lane); sxh_wire<2>(sr,si,lane);
  sxh_wire<3>(sr,si,lane); sxh_wire<4>(sr,si,lane); sxh_wire<5>(sr,si,lane);
  sxh_wire<6>(sr,si,lane); sxh_wire<7>(sr,si,lane); sxh_wire<8>(sr,si,lane);
  sxh_wire<9>(sr,si,lane);
  measure_store(sr,si,lane,dst+20);

  // rz3 (last layer)
  rz_wire<0>(sr,si,lane,rz3cs[0],rz3cs[1]);
  rz_wire<1>(sr,si,lane,rz3cs[2],rz3cs[3]);
  rz_wire<2>(sr,si,lane,rz3cs[4],rz3cs[5]);
  rz_wire<3>(sr,si,lane,rz3cs[6],rz3cs[7]);
  rz_wire<4>(sr,si,lane,rz3cs[8],rz3cs[9]);
  rz_wire<5>(sr,si,lane,rz3cs[10],rz3cs[11]);
  rz_wire<6>(sr,si,lane,rz3cs[12],rz3cs[13]);
  rz_wire<7>(sr,si,lane,rz3cs[14],rz3cs[15]);
  rz_wire<8>(sr,si,lane,rz3cs[16],rz3cs[17]);
  rz_wire<9>(sr,si,lane,rz3cs[18],rz3cs[19]);
  measure_store(sr,si,lane,dst+30);
}

// epilogue: x2 = relu(x@clin_w.T+clin_b); out = [x1,x2]@lin_w.T + lin_b
// block = 320 threads = 8 samples x 40 features
__global__ void k_epi(const float* __restrict__ x, const float* __restrict__ x1,
                      const float* __restrict__ clin_w, const float* __restrict__ clin_b,
                      const float* __restrict__ lin_w, const float* __restrict__ lin_b,
                      float* __restrict__ out)
{
  const int t = threadIdx.x;
  const int sl = t/40, f = t - sl*40;
  const int s = blockIdx.x*8 + sl;
  __shared__ float x2s[8][40];
  float acc = clin_b[f];
#pragma unroll
  for (int k=0;k<40;++k) acc = fmaf(x[s*40+k], clin_w[f*40+k], acc);
  x2s[sl][f] = fmaxf(acc, 0.f);
  __syncthreads();
  float o = lin_b[f];
#pragma unroll
  for (int j=0;j<40;++j) o = fmaf(x1[s*40+j], lin_w[f*80+j], o);
#pragma unroll
  for (int j=0;j<40;++j) o = fmaf(x2s[sl][j], lin_w[f*80+40+j], o);
  out[s*40+f] = o;
}

// ---------------- launch ---------------------------------------------------
extern "C" void kernel_launch(void* const* d_in, const int* in_sizes, int n_in,
                              void* d_out, int out_size, void* d_ws, size_t ws_size,
                              hipStream_t stream)
{
  const float* x      = (const float*)d_in[0];
  const float* qlin_w = (const float*)d_in[1];
  const float* qlin_b = (const float*)d_in[2];
  const float* bn_g   = (const float*)d_in[3];
  const float* bn_b   = (const float*)d_in[4];
  const float* clin_w = (const float*)d_in[5];
  const float* clin_b = (const float*)d_in[6];
  const float* lin_w  = (const float*)d_in[7];
  const float* lin_b  = (const float*)d_in[8];
  const float* rz1    = (const float*)d_in[9];
  const float* ry1    = (const float*)d_in[10];
  const float* rz2    = (const float*)d_in[11];
  const float* rz3    = (const float*)d_in[12];

  float* ws    = (float*)d_ws;
  float* xq    = ws + WS_XQ;
  float* x1    = ws + WS_X1;
  float* bn_a  = ws + WS_BNA;
  float* bn_c  = ws + WS_BNC;
  float* gates = ws + WS_GATES;
  float* rz3cs = ws + WS_RZ3;
  float* out   = (float*)d_out;

  hipLaunchKernelGGL(k_xq,     dim3(1280), dim3(256), 0, stream, x, qlin_w, qlin_b, xq);
  hipLaunchKernelGGL(k_stats,  dim3(40),   dim3(256), 0, stream, xq, bn_g, bn_b, bn_a, bn_c);
  hipLaunchKernelGGL(k_consts, dim3(1),    dim3(64),  0, stream, rz1, ry1, rz2, rz3, gates, rz3cs);
  hipLaunchKernelGGL(k_qnn,    dim3(2048), dim3(256), 0, stream, xq, bn_a, bn_c, gates, rz3cs, x1);
  hipLaunchKernelGGL(k_epi,    dim3(1024), dim3(320), 0, stream, x, x1, clin_w, clin_b, lin_w, lin_b, out);
}